// Round 1
// baseline (1296.872 us; speedup 1.0000x reference)
//
#include <hip/hip_runtime.h>
#include <math.h>

#define BATCH 128
#define OBS 512
#define ACT 7
#define NC 100
#define CTXD 128
#define HID 512
#define NROWS (BATCH*NC)   // 12800
#define QCOLS (ACT*NC)     // 700

// ---------------- init: zero context & q, row decomposition, action indices --
__global__ void init_kernel(const float* __restrict__ actions, float* __restrict__ ctx,
                            float* __restrict__ q, int* __restrict__ rowb,
                            float* __restrict__ rowc, int* __restrict__ jidx) {
    int idx = blockIdx.x * blockDim.x + threadIdx.x;
    if (idx < BATCH*QCOLS) q[idx] = 0.0f;
    if (idx < BATCH*CTXD) ctx[idx] = 0.0f;
    if (idx < NROWS) { rowb[idx] = idx / NC; rowc[idx] = (float)(idx % NC); }
    if (idx < BATCH*ACT) {
        float a = actions[idx];
        float v = floorf((a + 1.0f) / 2.0f * (float)NC);
        int j = (int)v;
        j = min(max(j, 0), NC - 1);
        jidx[idx] = j;
    }
}

// ---------------- Y0[b,h] = b1[h] + obs[b,:]@W1[0:512,h] + ctx[b,:]@W1[513:641,h]
__global__ void y0_kernel(const float* __restrict__ obs, const float* __restrict__ ctx,
                          const float* __restrict__ W1, const float* __restrict__ b1,
                          float* __restrict__ Y0) {
    int b = blockIdx.x;
    int h = blockIdx.y * 256 + threadIdx.x;
    float acc = b1[h];
    const float* orow = obs + b * OBS;
    const float* crow = ctx + b * CTXD;
    #pragma unroll 4
    for (int k = 0; k < OBS; ++k) acc = fmaf(orow[k], W1[k*HID + h], acc);
    #pragma unroll 4
    for (int k = 0; k < CTXD; ++k) acc = fmaf(crow[k], W1[(513+k)*HID + h], acc);
    Y0[b*HID + h] = acc;
}

// ---------------- GEMM2: H2[r,n] = relu( relu(Y0[b,k]+c*w1a[k]) @ W2[k,n] + b2[n] )
// Tile 128x128, K-tile 16, 256 threads, 8x8 micro-tile.
__launch_bounds__(256)
__global__ void gemm2_kernel(const float* __restrict__ Y0, const float* __restrict__ w1a,
                             const float* __restrict__ W2, const float* __restrict__ b2,
                             const int* __restrict__ rowb, const float* __restrict__ rowc,
                             float* __restrict__ H2) {
    __shared__ float As[16][128];
    __shared__ float Bs[16][128];
    const int r0 = blockIdx.x * 128;
    const int n0 = blockIdx.y * 128;
    const int tid = threadIdx.x;
    const int tx = tid % 16, ty = tid / 16;
    const int kA = tid / 16;           // 0..15 (k within tile for loads)
    const int mA = (tid % 16) * 8;     // 0..120 (m chunk for A loads / n chunk for B loads)

    // hoist per-row b,c for the 8 rows this thread stages
    int   bArr[8];
    float cArr[8];
    #pragma unroll
    for (int mm = 0; mm < 8; ++mm) {
        int row = r0 + mA + mm;
        bArr[mm] = rowb[row];
        cArr[mm] = rowc[row];
    }

    float acc[8][8] = {};

    for (int k0 = 0; k0 < HID; k0 += 16) {
        // stage A (implicit first layer): relu(Y0[b,k] + c*w1a[k])
        float wa = w1a[k0 + kA];
        #pragma unroll
        for (int mm = 0; mm < 8; ++mm) {
            float v = fmaf(cArr[mm], wa, Y0[bArr[mm]*HID + k0 + kA]);
            As[kA][mA + mm] = fmaxf(v, 0.0f);
        }
        // stage B: W2 tile
        const float4* src = reinterpret_cast<const float4*>(&W2[(size_t)(k0 + kA)*HID + n0 + mA]);
        float4 bv0 = src[0], bv1 = src[1];
        *reinterpret_cast<float4*>(&Bs[kA][mA])     = bv0;
        *reinterpret_cast<float4*>(&Bs[kA][mA + 4]) = bv1;
        __syncthreads();
        #pragma unroll
        for (int kk = 0; kk < 16; ++kk) {
            float a[8], bb[8];
            *reinterpret_cast<float4*>(&a[0])  = *reinterpret_cast<const float4*>(&As[kk][ty*8]);
            *reinterpret_cast<float4*>(&a[4])  = *reinterpret_cast<const float4*>(&As[kk][ty*8 + 4]);
            *reinterpret_cast<float4*>(&bb[0]) = *reinterpret_cast<const float4*>(&Bs[kk][tx*8]);
            *reinterpret_cast<float4*>(&bb[4]) = *reinterpret_cast<const float4*>(&Bs[kk][tx*8 + 4]);
            #pragma unroll
            for (int i = 0; i < 8; ++i)
                #pragma unroll
                for (int j = 0; j < 8; ++j)
                    acc[i][j] = fmaf(a[i], bb[j], acc[i][j]);
        }
        __syncthreads();
    }

    #pragma unroll
    for (int i = 0; i < 8; ++i) {
        int r = r0 + ty*8 + i;
        #pragma unroll
        for (int j = 0; j < 8; ++j) {
            int n = n0 + tx*8 + j;
            H2[(size_t)r*HID + n] = fmaxf(acc[i][j] + b2[n], 0.0f);
        }
    }
}

// ---------------- GEMM3: CC[r,n] = H2[r,:] @ W3[:,n] + b3[n] + ctx[b,n]
// Tile 64x64, K-tile 16, 256 threads, 4x4 micro-tile.
__launch_bounds__(256)
__global__ void gemm3_kernel(const float* __restrict__ H2, const float* __restrict__ W3,
                             const float* __restrict__ b3, const float* __restrict__ ctx,
                             const int* __restrict__ rowb, float* __restrict__ CC) {
    __shared__ float As[16][65];
    __shared__ float Bs[16][64];
    const int r0 = blockIdx.x * 64;
    const int n0 = blockIdx.y * 64;
    const int tid = threadIdx.x;
    const int tx = tid % 16, ty = tid / 16;

    float acc[4][4] = {};

    for (int k0 = 0; k0 < HID; k0 += 16) {
        // stage A: 64 rows x 16 k; thread loads 4 consecutive k for one row
        {
            int m = tid / 4, k4 = (tid % 4) * 4;
            float4 av = *reinterpret_cast<const float4*>(&H2[(size_t)(r0 + m)*HID + k0 + k4]);
            As[k4+0][m] = av.x; As[k4+1][m] = av.y; As[k4+2][m] = av.z; As[k4+3][m] = av.w;
        }
        // stage B: 16 k x 64 n
        {
            int kb = tid / 16, n4 = (tid % 16) * 4;
            float4 bv = *reinterpret_cast<const float4*>(&W3[(size_t)(k0 + kb)*CTXD + n0 + n4]);
            *reinterpret_cast<float4*>(&Bs[kb][n4]) = bv;
        }
        __syncthreads();
        #pragma unroll
        for (int kk = 0; kk < 16; ++kk) {
            float a[4], bb[4];
            a[0] = As[kk][ty*4+0]; a[1] = As[kk][ty*4+1];
            a[2] = As[kk][ty*4+2]; a[3] = As[kk][ty*4+3];
            *reinterpret_cast<float4*>(&bb[0]) = *reinterpret_cast<const float4*>(&Bs[kk][tx*4]);
            #pragma unroll
            for (int i = 0; i < 4; ++i)
                #pragma unroll
                for (int j = 0; j < 4; ++j)
                    acc[i][j] = fmaf(a[i], bb[j], acc[i][j]);
        }
        __syncthreads();
    }

    #pragma unroll
    for (int i = 0; i < 4; ++i) {
        int r = r0 + ty*4 + i;
        int b = rowb[r];
        #pragma unroll
        for (int j = 0; j < 4; ++j) {
            int n = n0 + tx*4 + j;
            CC[(size_t)r*CTXD + n] = acc[i][j] + b3[n] + ctx[b*CTXD + n];
        }
    }
}

// ---------------- q[b, qcol0 + c] = CC[r,:] @ Wp + bp
__global__ void q_kernel(const float* __restrict__ CC, const float* __restrict__ Wp,
                         const float* __restrict__ bp, float* __restrict__ q, int qcol0) {
    __shared__ float red[128];
    int r = blockIdx.x;
    int t = threadIdx.x;
    red[t] = CC[(size_t)r*CTXD + t] * Wp[t];
    __syncthreads();
    #pragma unroll
    for (int s = 64; s > 0; s >>= 1) {
        if (t < s) red[t] += red[t + s];
        __syncthreads();
    }
    if (t == 0) {
        int b = r / NC, c = r % NC;
        q[b*QCOLS + qcol0 + c] = red[0] + bp[0];
    }
}

// ---------------- context[b,:] = CC[b*NC + jidx[b,i], :]
__global__ void ctx_kernel(const float* __restrict__ CC, const int* __restrict__ jidx,
                           float* __restrict__ ctx, int i) {
    int b = blockIdx.x, t = threadIdx.x;
    int j = jidx[b*ACT + i];
    ctx[b*CTXD + t] = CC[(size_t)(b*NC + j)*CTXD + t];
}

// ---------------- out[b] = logsumexp(q[b, 0:700])
__global__ void lse_kernel(const float* __restrict__ q, float* __restrict__ out) {
    __shared__ float red[256];
    int b = blockIdx.x, t = threadIdx.x;
    float m = -INFINITY;
    for (int k = t; k < QCOLS; k += 256) m = fmaxf(m, q[b*QCOLS + k]);
    red[t] = m; __syncthreads();
    for (int s = 128; s > 0; s >>= 1) { if (t < s) red[t] = fmaxf(red[t], red[t+s]); __syncthreads(); }
    m = red[0]; __syncthreads();
    float sum = 0.0f;
    for (int k = t; k < QCOLS; k += 256) sum += expf(q[b*QCOLS + k] - m);
    red[t] = sum; __syncthreads();
    for (int s = 128; s > 0; s >>= 1) { if (t < s) red[t] += red[t+s]; __syncthreads(); }
    if (t == 0) out[b] = logf(red[0]) + m;
}

extern "C" void kernel_launch(void* const* d_in, const int* in_sizes, int n_in,
                              void* d_out, int out_size, void* d_ws, size_t ws_size,
                              hipStream_t stream) {
    const float* obs     = (const float*)d_in[0];
    const float* actions = (const float*)d_in[1];
    const float* W1      = (const float*)d_in[2];
    const float* b1      = (const float*)d_in[3];
    const float* W2      = (const float*)d_in[4];
    const float* b2      = (const float*)d_in[5];
    const float* W3      = (const float*)d_in[6];
    const float* b3      = (const float*)d_in[7];
    const float* Wp      = (const float*)d_in[8];
    const float* bp      = (const float*)d_in[9];
    float* out = (float*)d_out;
    float* ws  = (float*)d_ws;

    // workspace layout (floats), all 16B aligned
    float* ctx  = ws + 0;         // 16384
    float* Y0   = ws + 16384;     // 65536
    float* H2   = ws + 81920;     // 6,553,600
    float* CC   = ws + 6635520;   // 1,638,400
    float* q    = ws + 8273920;   // 89,600
    int*   rowb = (int*)  (ws + 8363520); // 12800
    float* rowc =          ws + 8376320;  // 12800
    int*   jidx = (int*)  (ws + 8389120); // 896

    init_kernel<<<(BATCH*QCOLS + 255)/256, 256, 0, stream>>>(actions, ctx, q, rowb, rowc, jidx);

    for (int i = 1; i < ACT; ++i) {
        const float* W1i = W1 + (size_t)i * 641 * HID;
        const float* w1a = W1i + (size_t)512 * HID;
        y0_kernel<<<dim3(BATCH, 2), 256, 0, stream>>>(obs, ctx, W1i, b1 + i*HID, Y0);
        gemm2_kernel<<<dim3(NROWS/128, HID/128), 256, 0, stream>>>(
            Y0, w1a, W2 + (size_t)i*HID*HID, b2 + i*HID, rowb, rowc, H2);
        gemm3_kernel<<<dim3(NROWS/64, CTXD/64), 256, 0, stream>>>(
            H2, W3 + (size_t)i*HID*CTXD, b3 + i*CTXD, ctx, rowb, CC);
        q_kernel<<<NROWS, 128, 0, stream>>>(CC, Wp, bp, q, (i-1)*NC);
        ctx_kernel<<<BATCH, CTXD, 0, stream>>>(CC, jidx, ctx, i);
    }

    lse_kernel<<<BATCH, 256, 0, stream>>>(q, out);
}

// Round 2
// 366.714 us; speedup vs baseline: 3.5365x; 3.5365x over previous
//
#include <hip/hip_runtime.h>
#include <math.h>

#define BATCH 128
#define ACT 7
#define NC 100
#define CTXD 128
#define HID 512
#define NROWS (BATCH*NC)   // 12800
#define QCOLS (ACT*NC)     // 700

typedef __attribute__((ext_vector_type(8))) __bf16 bf16x8;
typedef __attribute__((ext_vector_type(4))) float f32x4;
typedef __attribute__((ext_vector_type(8))) unsigned short u16x8;

__device__ __forceinline__ unsigned short f2bf(float f) {
    union { float f; unsigned int u; } v; v.f = f;
    unsigned int u = v.u;
    return (unsigned short)((u + 0x7fffu + ((u >> 16) & 1u)) >> 16);
}

// async global->LDS, 16B per lane. LDS dest = wave-uniform base + lane*16.
__device__ __forceinline__ void async16(const void* g, void* l) {
    __builtin_amdgcn_global_load_lds(
        (const __attribute__((address_space(1))) unsigned int*)(uintptr_t)g,
        (__attribute__((address_space(3))) unsigned int*)(unsigned int)(uintptr_t)l,
        16, 0, 0);
}

// ---------------- init: zero q & ctx0, discretize actions --------------------
__global__ void init_kernel(const float* __restrict__ actions, float* __restrict__ ctx0,
                            float* __restrict__ q, int* __restrict__ jidx) {
    int idx = blockIdx.x * blockDim.x + threadIdx.x;
    if (idx < BATCH*QCOLS) q[idx] = 0.0f;
    if (idx < BATCH*CTXD) ctx0[idx] = 0.0f;
    if (idx < BATCH*ACT) {
        float a = actions[idx];
        int j = (int)floorf((a + 1.0f) * 50.0f);   // (a+1)/2*100
        jidx[idx] = min(max(j, 0), NC - 1);
    }
}

// ---------------- obs -> bf16 ------------------------------------------------
__global__ void obscvt_kernel(const float* __restrict__ obs, unsigned short* __restrict__ obs_bf) {
    int i = blockIdx.x * 256 + threadIdx.x;   // 65536 total
    obs_bf[i] = f2bf(obs[i]);
}

// ---------------- transpose+convert: out_bf[z][c][r] = in_f32[z+1][r][c] -----
__global__ void transpose_bf(const float* __restrict__ in, unsigned short* __restrict__ out,
                             int R, int Cn, size_t inStride, size_t outStride) {
    __shared__ float tile[32][33];
    const float* ip = in + (size_t)(blockIdx.z + 1) * inStride;
    unsigned short* op = out + (size_t)blockIdx.z * outStride;
    int r0 = blockIdx.x * 32, c0 = blockIdx.y * 32;
    int tx = threadIdx.x, ty = threadIdx.y;  // 32 x 8
    #pragma unroll
    for (int j = 0; j < 32; j += 8)
        tile[ty + j][tx] = ip[(size_t)(r0 + ty + j) * Cn + c0 + tx];
    __syncthreads();
    #pragma unroll
    for (int j = 0; j < 32; j += 8)
        op[(size_t)(c0 + ty + j) * R + r0 + tx] = f2bf(tile[tx][ty + j]);
}

// ---------------- Yobs[z][b][h] = obs@W1A[z+1] + b1[z+1]  (MFMA 64x128 tile) -
__launch_bounds__(256)
__global__ void yobs_kernel(const unsigned short* __restrict__ A,      // obs_bf [128][512]
                            const unsigned short* __restrict__ BtAll,  // W1AT [6][512][512]
                            const float* __restrict__ b1,
                            float* __restrict__ Yobs) {
    __shared__ unsigned short As[64*32];
    __shared__ unsigned short Bs[128*32];
    const int m0 = blockIdx.x * 64;
    const int n0 = blockIdx.y * 128;
    const int z  = blockIdx.z;
    const unsigned short* Bt = BtAll + (size_t)z * 262144;
    const int tid = threadIdx.x, lane = tid & 63, wave = tid >> 6;
    const int wm = wave >> 1, wn = wave & 1;
    const int srow = tid >> 2, skc = (tid & 3) * 8;
    const unsigned short* gA  = A  + (size_t)(m0 + srow) * HID + skc;
    const unsigned short* gB0 = Bt + (size_t)(n0 + srow) * HID + skc;
    const unsigned short* gB1 = gB0 + 64 * HID;
    unsigned short* lA  = As + tid * 8;
    unsigned short* lB0 = Bs + tid * 8;
    unsigned short* lB1 = Bs + 2048 + tid * 8;
    f32x4 acc[2][4] = {};
    for (int k0 = 0; k0 < HID; k0 += 32) {
        async16(gA + k0, lA);
        async16(gB0 + k0, lB0);
        async16(gB1 + k0, lB1);
        __syncthreads();
        const int q8 = (lane >> 4) * 8;
        bf16x8 af[2], bfr[4];
        #pragma unroll
        for (int mt = 0; mt < 2; ++mt)
            af[mt] = *(const bf16x8*)(As + ((wm*32 + mt*16 + (lane & 15)) * 32 + q8));
        #pragma unroll
        for (int nt = 0; nt < 4; ++nt)
            bfr[nt] = *(const bf16x8*)(Bs + ((wn*64 + nt*16 + (lane & 15)) * 32 + q8));
        #pragma unroll
        for (int mt = 0; mt < 2; ++mt)
            #pragma unroll
            for (int nt = 0; nt < 4; ++nt)
                acc[mt][nt] = __builtin_amdgcn_mfma_f32_16x16x32_bf16(af[mt], bfr[nt], acc[mt][nt], 0, 0, 0);
        __syncthreads();
    }
    const int colL = wn*64 + (lane & 15);
    #pragma unroll
    for (int nt = 0; nt < 4; ++nt) {
        const int col = n0 + colL + nt*16;
        const float bb = b1[(z + 1) * HID + col];
        #pragma unroll
        for (int mt = 0; mt < 2; ++mt)
            #pragma unroll
            for (int r = 0; r < 4; ++r) {
                const int row = m0 + wm*32 + mt*16 + (lane >> 4)*4 + r;
                Yobs[(size_t)z * BATCH * HID + (size_t)row * HID + col] = acc[mt][nt][r] + bb;
            }
    }
}

// ---------------- Y0[b][h] = Yobs_i[b][h] + ctx[b][:]@W1C[:, h] --------------
__launch_bounds__(512)
__global__ void y0c_kernel(const float* __restrict__ Yobs_i, const float* __restrict__ ctx,
                           const float* __restrict__ W1C, float* __restrict__ Y0) {
    const int b = blockIdx.x, h = threadIdx.x;
    __shared__ float cs[CTXD];
    if (h < CTXD) cs[h] = ctx[b * CTXD + h];
    __syncthreads();
    float a0 = 0.f, a1 = 0.f, a2 = 0.f, a3 = 0.f;
    #pragma unroll 8
    for (int k = 0; k < CTXD; k += 4) {
        a0 = fmaf(cs[k],     W1C[(size_t)(k)     * HID + h], a0);
        a1 = fmaf(cs[k + 1], W1C[(size_t)(k + 1) * HID + h], a1);
        a2 = fmaf(cs[k + 2], W1C[(size_t)(k + 2) * HID + h], a2);
        a3 = fmaf(cs[k + 3], W1C[(size_t)(k + 3) * HID + h], a3);
    }
    Y0[b * HID + h] = Yobs_i[b * HID + h] + ((a0 + a1) + (a2 + a3));
}

// ---------------- H1bf[r][k] = bf16(relu(Y0[b][k] + c*w1a[k])) ---------------
__global__ void h1_kernel(const float* __restrict__ Y0, const float* __restrict__ w1a,
                          unsigned short* __restrict__ H1) {
    const int t = blockIdx.x * 256 + threadIdx.x;   // 12800*64
    const int r = t >> 6, kc = (t & 63) << 3;
    const int b = r / NC;
    const float c = (float)(r - b * NC);
    const float4* yp = (const float4*)(Y0 + b * HID + kc);
    const float4* wp = (const float4*)(w1a + kc);
    float4 ya = yp[0], yb = yp[1], wa = wp[0], wb = wp[1];
    u16x8 o;
    o[0] = f2bf(fmaxf(fmaf(c, wa.x, ya.x), 0.f));
    o[1] = f2bf(fmaxf(fmaf(c, wa.y, ya.y), 0.f));
    o[2] = f2bf(fmaxf(fmaf(c, wa.z, ya.z), 0.f));
    o[3] = f2bf(fmaxf(fmaf(c, wa.w, ya.w), 0.f));
    o[4] = f2bf(fmaxf(fmaf(c, wb.x, yb.x), 0.f));
    o[5] = f2bf(fmaxf(fmaf(c, wb.y, yb.y), 0.f));
    o[6] = f2bf(fmaxf(fmaf(c, wb.z, yb.z), 0.f));
    o[7] = f2bf(fmaxf(fmaf(c, wb.w, yb.w), 0.f));
    *(u16x8*)(H1 + (size_t)r * HID + kc) = o;
}

// ---------------- GEMM2: H2bf = bf16(relu(H1 @ W2 + b2)), 128x128 tiles ------
__launch_bounds__(256)
__global__ void gemm2_kernel(const unsigned short* __restrict__ A,   // H1 [12800][512]
                             const unsigned short* __restrict__ Bt,  // W2T [512][512]
                             const float* __restrict__ b2,
                             unsigned short* __restrict__ C) {
    __shared__ unsigned short As[128*32];
    __shared__ unsigned short Bs[128*32];
    const int m0 = blockIdx.x * 128, n0 = blockIdx.y * 128;
    const int tid = threadIdx.x, lane = tid & 63, wave = tid >> 6;
    const int wm = wave >> 1, wn = wave & 1;
    const int srow = tid >> 2, skc = (tid & 3) * 8;
    const unsigned short* gA0 = A  + (size_t)(m0 + srow) * HID + skc;
    const unsigned short* gA1 = gA0 + 64 * HID;
    const unsigned short* gB0 = Bt + (size_t)(n0 + srow) * HID + skc;
    const unsigned short* gB1 = gB0 + 64 * HID;
    unsigned short* lA0 = As + tid * 8;
    unsigned short* lA1 = As + 2048 + tid * 8;
    unsigned short* lB0 = Bs + tid * 8;
    unsigned short* lB1 = Bs + 2048 + tid * 8;
    f32x4 acc[4][4] = {};
    for (int k0 = 0; k0 < HID; k0 += 32) {
        async16(gA0 + k0, lA0); async16(gA1 + k0, lA1);
        async16(gB0 + k0, lB0); async16(gB1 + k0, lB1);
        __syncthreads();
        const int q8 = (lane >> 4) * 8;
        bf16x8 af[4], bfr[4];
        #pragma unroll
        for (int mt = 0; mt < 4; ++mt)
            af[mt] = *(const bf16x8*)(As + ((wm*64 + mt*16 + (lane & 15)) * 32 + q8));
        #pragma unroll
        for (int nt = 0; nt < 4; ++nt)
            bfr[nt] = *(const bf16x8*)(Bs + ((wn*64 + nt*16 + (lane & 15)) * 32 + q8));
        #pragma unroll
        for (int mt = 0; mt < 4; ++mt)
            #pragma unroll
            for (int nt = 0; nt < 4; ++nt)
                acc[mt][nt] = __builtin_amdgcn_mfma_f32_16x16x32_bf16(af[mt], bfr[nt], acc[mt][nt], 0, 0, 0);
        __syncthreads();
    }
    const int colB = n0 + wn*64 + (lane & 15);
    #pragma unroll
    for (int nt = 0; nt < 4; ++nt) {
        const int col = colB + nt*16;
        const float bb = b2[col];
        #pragma unroll
        for (int mt = 0; mt < 4; ++mt)
            #pragma unroll
            for (int r = 0; r < 4; ++r) {
                const int row = m0 + wm*64 + mt*16 + (lane >> 4)*4 + r;
                C[(size_t)row * HID + col] = f2bf(fmaxf(acc[mt][nt][r] + bb, 0.f));
            }
    }
}

// ---------------- GEMM3 fused: CC = H2@W3 + b3 + ctx; q = CC@Wp + bp; ctx sel
__launch_bounds__(256)
__global__ void gemm3f_kernel(const unsigned short* __restrict__ A,   // H2 [12800][512]
                              const unsigned short* __restrict__ Bt,  // W3T [128][512]
                              const float* __restrict__ b3,
                              const float* __restrict__ ctx_cur,
                              float* __restrict__ ctx_nxt,
                              const float* __restrict__ Wp,
                              const float* __restrict__ bp,
                              const int* __restrict__ jidx,
                              float* __restrict__ q, int ii) {
    __shared__ unsigned short As[64*32];
    __shared__ unsigned short Bs[128*32];
    __shared__ float CCs[64][132];
    __shared__ float qpart[64][4];
    const int m0 = blockIdx.x * 64;
    const int tid = threadIdx.x, lane = tid & 63, wave = tid >> 6;
    const int wm = wave >> 1, wn = wave & 1;
    const int srow = tid >> 2, skc = (tid & 3) * 8;
    const unsigned short* gA  = A  + (size_t)(m0 + srow) * HID + skc;
    const unsigned short* gB0 = Bt + (size_t)srow * HID + skc;
    const unsigned short* gB1 = gB0 + 64 * HID;
    unsigned short* lA  = As + tid * 8;
    unsigned short* lB0 = Bs + tid * 8;
    unsigned short* lB1 = Bs + 2048 + tid * 8;
    f32x4 acc[2][4] = {};
    for (int k0 = 0; k0 < HID; k0 += 32) {
        async16(gA + k0, lA);
        async16(gB0 + k0, lB0);
        async16(gB1 + k0, lB1);
        __syncthreads();
        const int q8 = (lane >> 4) * 8;
        bf16x8 af[2], bfr[4];
        #pragma unroll
        for (int mt = 0; mt < 2; ++mt)
            af[mt] = *(const bf16x8*)(As + ((wm*32 + mt*16 + (lane & 15)) * 32 + q8));
        #pragma unroll
        for (int nt = 0; nt < 4; ++nt)
            bfr[nt] = *(const bf16x8*)(Bs + ((wn*64 + nt*16 + (lane & 15)) * 32 + q8));
        #pragma unroll
        for (int mt = 0; mt < 2; ++mt)
            #pragma unroll
            for (int nt = 0; nt < 4; ++nt)
                acc[mt][nt] = __builtin_amdgcn_mfma_f32_16x16x32_bf16(af[mt], bfr[nt], acc[mt][nt], 0, 0, 0);
        __syncthreads();
    }
    // epilogue: CC tile to LDS (add b3 + ctx residual)
    const int colL = wn*64 + (lane & 15);
    #pragma unroll
    for (int nt = 0; nt < 4; ++nt) {
        const int col = colL + nt*16;
        const float bb = b3[col];
        #pragma unroll
        for (int mt = 0; mt < 2; ++mt)
            #pragma unroll
            for (int r = 0; r < 4; ++r) {
                const int rowL = wm*32 + mt*16 + (lane >> 4)*4 + r;
                const int gb = (m0 + rowL) / NC;
                CCs[rowL][col] = acc[mt][nt][r] + bb + ctx_cur[gb * CTXD + col];
            }
    }
    __syncthreads();
    // q reduction: 4 threads per row, 32 cols each
    {
        const int rowL = tid >> 2, seg = tid & 3;
        float s = 0.f;
        #pragma unroll
        for (int j = 0; j < 32; ++j) {
            const int col = seg*32 + j;
            s += CCs[rowL][col] * Wp[col];
        }
        qpart[rowL][seg] = s;
    }
    __syncthreads();
    if (tid < 64) {
        const int gr = m0 + tid;
        const int gb = gr / NC, gc = gr - gb * NC;
        q[gb * QCOLS + (ii - 1) * NC + gc] =
            qpart[tid][0] + qpart[tid][1] + qpart[tid][2] + qpart[tid][3] + bp[0];
    }
    // ctx select: row with c == jidx[b][ii] becomes next context for batch b
    for (int rr = 0; rr < 64; ++rr) {
        const int gr = m0 + rr;
        const int gb = gr / NC, gc = gr - gb * NC;
        if (jidx[gb * ACT + ii] == gc) {
            if (tid < CTXD) ctx_nxt[gb * CTXD + tid] = CCs[rr][tid];
        }
    }
}

// ---------------- out[b] = logsumexp(q[b, 0:700]) ----------------------------
__global__ void lse_kernel(const float* __restrict__ q, float* __restrict__ out) {
    __shared__ float red[256];
    int b = blockIdx.x, t = threadIdx.x;
    float m = -INFINITY;
    for (int k = t; k < QCOLS; k += 256) m = fmaxf(m, q[b*QCOLS + k]);
    red[t] = m; __syncthreads();
    for (int s = 128; s > 0; s >>= 1) { if (t < s) red[t] = fmaxf(red[t], red[t+s]); __syncthreads(); }
    m = red[0]; __syncthreads();
    float sum = 0.0f;
    for (int k = t; k < QCOLS; k += 256) sum += expf(q[b*QCOLS + k] - m);
    red[t] = sum; __syncthreads();
    for (int s = 128; s > 0; s >>= 1) { if (t < s) red[t] += red[t+s]; __syncthreads(); }
    if (t == 0) out[b] = logf(red[0]) + m;
}

extern "C" void kernel_launch(void* const* d_in, const int* in_sizes, int n_in,
                              void* d_out, int out_size, void* d_ws, size_t ws_size,
                              hipStream_t stream) {
    const float* obs     = (const float*)d_in[0];
    const float* actions = (const float*)d_in[1];
    const float* W1      = (const float*)d_in[2];
    const float* b1      = (const float*)d_in[3];
    const float* W2      = (const float*)d_in[4];
    const float* b2      = (const float*)d_in[5];
    const float* W3      = (const float*)d_in[6];
    const float* b3      = (const float*)d_in[7];
    const float* Wp      = (const float*)d_in[8];
    const float* bp      = (const float*)d_in[9];
    float* out = (float*)d_out;
    float* ws  = (float*)d_ws;

    // workspace layout (float offsets), total 8,151,552 floats = 32.6 MB
    float* ctxA = ws;                                      // 16384
    float* ctxB = ws + 16384;                              // 16384
    float* q    = ws + 32768;                              // 89600
    int*   jidx = (int*)(ws + 122368);                     // 896 (slot 1024)
    unsigned short* obs_bf = (unsigned short*)(ws + 123392);   // 65536 us
    float* Yobs = ws + 156160;                             // 6*65536
    float* Y0   = ws + 549376;                             // 65536
    unsigned short* W2T = (unsigned short*)(ws + 614912);  // 6*262144 us
    unsigned short* W3T = (unsigned short*)(ws + 1401344); // 6*65536 us
    unsigned short* H1  = (unsigned short*)(ws + 1597952); // 12800*512 us
    unsigned short* W1AT = H1;  // alias: W1AT only needed before first h1_kernel
    unsigned short* H2  = (unsigned short*)(ws + 4874752); // 12800*512 us

    init_kernel<<<(BATCH*QCOLS + 255)/256, 256, 0, stream>>>(actions, ctxA, q, jidx);
    obscvt_kernel<<<BATCH*HID/256, 256, 0, stream>>>(obs, obs_bf);
    transpose_bf<<<dim3(16,16,6), dim3(32,8), 0, stream>>>(W1, W1AT, 512, 512, (size_t)641*512, (size_t)512*512);
    transpose_bf<<<dim3(16,16,6), dim3(32,8), 0, stream>>>(W2, W2T, 512, 512, (size_t)512*512, (size_t)512*512);
    transpose_bf<<<dim3(16, 4,6), dim3(32,8), 0, stream>>>(W3, W3T, 512, 128, (size_t)512*128, (size_t)128*512);
    yobs_kernel<<<dim3(2,4,6), 256, 0, stream>>>(obs_bf, W1AT, b1, Yobs);

    float* cur = ctxA; float* nxt = ctxB;
    for (int i = 1; i < ACT; ++i) {
        const float* W1i = W1 + (size_t)i * 641 * HID;
        y0c_kernel<<<BATCH, 512, 0, stream>>>(Yobs + (size_t)(i-1)*BATCH*HID, cur, W1i + (size_t)513*HID, Y0);
        h1_kernel<<<NROWS*64/256, 256, 0, stream>>>(Y0, W1i + (size_t)512*HID, H1);
        gemm2_kernel<<<dim3(NROWS/128, HID/128), 256, 0, stream>>>(
            H1, W2T + (size_t)(i-1)*262144, b2 + i*HID, H2);
        gemm3f_kernel<<<NROWS/64, 256, 0, stream>>>(
            H2, W3T + (size_t)(i-1)*65536, b3 + i*CTXD, cur, nxt, Wp, bp, jidx, q, i);
        float* tsw = cur; cur = nxt; nxt = tsw;
    }

    lse_kernel<<<BATCH, 256, 0, stream>>>(q, out);
}

// Round 3
// 366.067 us; speedup vs baseline: 3.5427x; 1.0018x over previous
//
#include <hip/hip_runtime.h>
#include <math.h>

#define BATCH 128
#define ACT 7
#define NC 100
#define CTXD 128
#define HID 512
#define NROWS (BATCH*NC)   // 12800
#define QCOLS (ACT*NC)     // 700

typedef __attribute__((ext_vector_type(8))) __bf16 bf16x8;
typedef __attribute__((ext_vector_type(4))) float f32x4;
typedef __attribute__((ext_vector_type(8))) unsigned short u16x8;

__device__ __forceinline__ unsigned short f2bf(float f) {
    union { float f; unsigned int u; } v; v.f = f;
    unsigned int u = v.u;
    return (unsigned short)((u + 0x7fffu + ((u >> 16) & 1u)) >> 16);
}

// async global->LDS, 16B per lane. LDS dest = wave-uniform base + lane*16.
__device__ __forceinline__ void async16(const void* g, void* l) {
    __builtin_amdgcn_global_load_lds(
        (const __attribute__((address_space(1))) unsigned int*)(uintptr_t)g,
        (__attribute__((address_space(3))) unsigned int*)(unsigned int)(uintptr_t)l,
        16, 0, 0);
}

// ---------------- init: zero q & ctx0, discretize actions --------------------
__global__ void init_kernel(const float* __restrict__ actions, float* __restrict__ ctx0,
                            float* __restrict__ q, int* __restrict__ jidx) {
    int idx = blockIdx.x * blockDim.x + threadIdx.x;
    if (idx < BATCH*QCOLS) q[idx] = 0.0f;
    if (idx < BATCH*CTXD) ctx0[idx] = 0.0f;
    if (idx < BATCH*ACT) {
        float a = actions[idx];
        int j = (int)floorf((a + 1.0f) * 50.0f);   // (a+1)/2*100
        jidx[idx] = min(max(j, 0), NC - 1);
    }
}

// ---------------- obs -> bf16 ------------------------------------------------
__global__ void obscvt_kernel(const float* __restrict__ obs, unsigned short* __restrict__ obs_bf) {
    int i = blockIdx.x * 256 + threadIdx.x;   // 65536 total
    obs_bf[i] = f2bf(obs[i]);
}

// ---------------- merged transpose+convert for W1A / W2 / W3 -----------------
// z 0..5: W1A[z+1] rows 0..511 -> W1AT[z] [512][512]
// z 6..11: W2[z-5]            -> W2T  [512][512]
// z 12..17: W3[z-11]          -> W3T  [128][512]   (only blockIdx.y < 4)
__global__ void prep_transpose(const float* __restrict__ W1, const float* __restrict__ W2,
                               const float* __restrict__ W3,
                               unsigned short* __restrict__ W1AT, unsigned short* __restrict__ W2T,
                               unsigned short* __restrict__ W3T) {
    __shared__ float tile[32][33];
    const int z = blockIdx.z;
    const float* ip; unsigned short* op; int Cn;
    if (z < 6)       { ip = W1 + (size_t)(z + 1) * 641 * 512; op = W1AT + (size_t)z * 262144; Cn = 512; }
    else if (z < 12) { int i = z - 6;  ip = W2 + (size_t)(i + 1) * 262144; op = W2T + (size_t)i * 262144; Cn = 512; }
    else             { int i = z - 12; ip = W3 + (size_t)(i + 1) * 65536;  op = W3T + (size_t)i * 65536;  Cn = 128;
                       if (blockIdx.y >= 4) return; }
    const int r0 = blockIdx.x * 32, c0 = blockIdx.y * 32;
    const int tx = threadIdx.x, ty = threadIdx.y;  // 32 x 8
    #pragma unroll
    for (int j = 0; j < 32; j += 8)
        tile[ty + j][tx] = ip[(size_t)(r0 + ty + j) * Cn + c0 + tx];
    __syncthreads();
    #pragma unroll
    for (int j = 0; j < 32; j += 8)
        op[(size_t)(c0 + ty + j) * 512 + r0 + tx] = f2bf(tile[tx][ty + j]);
}

// ---------------- Yobs[z][b][h] = obs@W1A[z+1] + b1[z+1]  (MFMA 64x128 tile) -
__launch_bounds__(256)
__global__ void yobs_kernel(const unsigned short* __restrict__ A,      // obs_bf [128][512]
                            const unsigned short* __restrict__ BtAll,  // W1AT [6][512][512]
                            const float* __restrict__ b1,
                            float* __restrict__ Yobs) {
    __shared__ unsigned short As[64*32];
    __shared__ unsigned short Bs[128*32];
    const int m0 = blockIdx.x * 64;
    const int n0 = blockIdx.y * 128;
    const int z  = blockIdx.z;
    const unsigned short* Bt = BtAll + (size_t)z * 262144;
    const int tid = threadIdx.x, lane = tid & 63, wave = tid >> 6;
    const int wm = wave >> 1, wn = wave & 1;
    const int srow = tid >> 2, skc = (tid & 3) * 8;
    const unsigned short* gA  = A  + (size_t)(m0 + srow) * HID + skc;
    const unsigned short* gB0 = Bt + (size_t)(n0 + srow) * HID + skc;
    const unsigned short* gB1 = gB0 + 64 * HID;
    unsigned short* lA  = As + tid * 8;
    unsigned short* lB0 = Bs + tid * 8;
    unsigned short* lB1 = Bs + 2048 + tid * 8;
    f32x4 acc[2][4] = {};
    for (int k0 = 0; k0 < HID; k0 += 32) {
        async16(gA + k0, lA);
        async16(gB0 + k0, lB0);
        async16(gB1 + k0, lB1);
        __syncthreads();
        const int q8 = (lane >> 4) * 8;
        bf16x8 af[2], bfr[4];
        #pragma unroll
        for (int mt = 0; mt < 2; ++mt)
            af[mt] = *(const bf16x8*)(As + ((wm*32 + mt*16 + (lane & 15)) * 32 + q8));
        #pragma unroll
        for (int nt = 0; nt < 4; ++nt)
            bfr[nt] = *(const bf16x8*)(Bs + ((wn*64 + nt*16 + (lane & 15)) * 32 + q8));
        #pragma unroll
        for (int mt = 0; mt < 2; ++mt)
            #pragma unroll
            for (int nt = 0; nt < 4; ++nt)
                acc[mt][nt] = __builtin_amdgcn_mfma_f32_16x16x32_bf16(af[mt], bfr[nt], acc[mt][nt], 0, 0, 0);
        __syncthreads();
    }
    const int colL = wn*64 + (lane & 15);
    #pragma unroll
    for (int nt = 0; nt < 4; ++nt) {
        const int col = n0 + colL + nt*16;
        const float bb = b1[(z + 1) * HID + col];
        #pragma unroll
        for (int mt = 0; mt < 2; ++mt)
            #pragma unroll
            for (int r = 0; r < 4; ++r) {
                const int row = m0 + wm*32 + mt*16 + (lane >> 4)*4 + r;
                Yobs[(size_t)z * BATCH * HID + (size_t)row * HID + col] = acc[mt][nt][r] + bb;
            }
    }
}

// ---------------- fused y0 + h1: per (batch, half) block ---------------------
// y0[h] = Yobs_i[b][h] + ctx[b][:]@W1C[:,h];  H1[b*100+c][h] = bf16(relu(y0[h]+c*w1a[h]))
__launch_bounds__(256)
__global__ void y0h1_kernel(const float* __restrict__ Yobs_i, const float* __restrict__ ctx,
                            const float* __restrict__ W1C, const float* __restrict__ w1a,
                            unsigned short* __restrict__ H1) {
    const int b = blockIdx.x >> 1;
    const int h0 = (blockIdx.x & 1) * 256;
    const int tid = threadIdx.x;
    __shared__ float cs[CTXD];
    __shared__ float ys[256];
    __shared__ float wsh[256];
    if (tid < CTXD) cs[tid] = ctx[b * CTXD + tid];
    __syncthreads();
    const int h = h0 + tid;
    float acc = Yobs_i[b * HID + h];
    #pragma unroll 4
    for (int k = 0; k < CTXD; ++k) acc = fmaf(cs[k], W1C[(size_t)k * HID + h], acc);
    ys[tid] = acc;
    wsh[tid] = w1a[h];
    __syncthreads();
    // write 100 rows x 256 cols (this half), 8 rows per pass, 16B/lane stores
    const int colc = (tid & 31) * 8;
    const int rsub = tid >> 5;            // 0..7
    float yv[8], wv[8];
    #pragma unroll
    for (int e = 0; e < 8; ++e) { yv[e] = ys[colc + e]; wv[e] = wsh[colc + e]; }
    for (int pass = 0; pass < 13; ++pass) {
        const int row = pass * 8 + rsub;
        if (row < NC) {
            const float c = (float)row;
            u16x8 o;
            #pragma unroll
            for (int e = 0; e < 8; ++e)
                o[e] = f2bf(fmaxf(fmaf(c, wv[e], yv[e]), 0.f));
            *(u16x8*)(H1 + (size_t)(b * NC + row) * HID + h0 + colc) = o;
        }
    }
}

// ---------------- GEMM2: H2bf = bf16(relu(H1 @ W2 + b2)), 128x128, BK=64 -----
__launch_bounds__(256)
__global__ void gemm2_kernel(const unsigned short* __restrict__ A,   // H1 [12800][512]
                             const unsigned short* __restrict__ Bt,  // W2T [512][512]
                             const float* __restrict__ b2,
                             unsigned short* __restrict__ C) {
    __shared__ unsigned short As[2][128*32];
    __shared__ unsigned short Bs[2][128*32];
    const int m0 = blockIdx.x * 128, n0 = blockIdx.y * 128;
    const int tid = threadIdx.x, lane = tid & 63, wave = tid >> 6;
    const int wm = wave >> 1, wn = wave & 1;
    const int srow = tid >> 2, skc = (tid & 3) * 8;
    const int l15 = lane & 15, q8 = (lane >> 4) * 8;
    const unsigned short* gA0 = A  + (size_t)(m0 + srow) * HID + skc;
    const unsigned short* gA1 = gA0 + 64 * HID;
    const unsigned short* gB0 = Bt + (size_t)(n0 + srow) * HID + skc;
    const unsigned short* gB1 = gB0 + 64 * HID;
    f32x4 acc[4][4] = {};
    for (int k0 = 0; k0 < HID; k0 += 64) {
        async16(gA0 + k0,      As[0] + tid*8);
        async16(gA1 + k0,      As[0] + 2048 + tid*8);
        async16(gA0 + k0 + 32, As[1] + tid*8);
        async16(gA1 + k0 + 32, As[1] + 2048 + tid*8);
        async16(gB0 + k0,      Bs[0] + tid*8);
        async16(gB1 + k0,      Bs[0] + 2048 + tid*8);
        async16(gB0 + k0 + 32, Bs[1] + tid*8);
        async16(gB1 + k0 + 32, Bs[1] + 2048 + tid*8);
        __syncthreads();
        #pragma unroll
        for (int h = 0; h < 2; ++h) {
            bf16x8 af[4], bfr[4];
            #pragma unroll
            for (int mt = 0; mt < 4; ++mt)
                af[mt] = *(const bf16x8*)(As[h] + (wm*64 + mt*16 + l15) * 32 + q8);
            #pragma unroll
            for (int nt = 0; nt < 4; ++nt)
                bfr[nt] = *(const bf16x8*)(Bs[h] + (wn*64 + nt*16 + l15) * 32 + q8);
            #pragma unroll
            for (int mt = 0; mt < 4; ++mt)
                #pragma unroll
                for (int nt = 0; nt < 4; ++nt)
                    acc[mt][nt] = __builtin_amdgcn_mfma_f32_16x16x32_bf16(af[mt], bfr[nt], acc[mt][nt], 0, 0, 0);
        }
        __syncthreads();
    }
    const int colB = n0 + wn*64 + l15;
    #pragma unroll
    for (int nt = 0; nt < 4; ++nt) {
        const int col = colB + nt*16;
        const float bb = b2[col];
        #pragma unroll
        for (int mt = 0; mt < 4; ++mt)
            #pragma unroll
            for (int r = 0; r < 4; ++r) {
                const int row = m0 + wm*64 + mt*16 + (lane >> 4)*4 + r;
                C[(size_t)row * HID + col] = f2bf(fmaxf(acc[mt][nt][r] + bb, 0.f));
            }
    }
}

// ---------------- GEMM3 fused: M=32 tiles (400 blocks), BK=64 ----------------
// CC = H2@W3 + b3 + ctx; q = CC@Wp + bp; ctx_nxt select
__launch_bounds__(256)
__global__ void gemm3f_kernel(const unsigned short* __restrict__ A,   // H2 [12800][512]
                              const unsigned short* __restrict__ Bt,  // W3T [128][512]
                              const float* __restrict__ b3,
                              const float* __restrict__ ctx_cur,
                              float* __restrict__ ctx_nxt,
                              const float* __restrict__ Wp,
                              const float* __restrict__ bp,
                              const int* __restrict__ jidx,
                              float* __restrict__ q, int ii) {
    __shared__ unsigned short As[2][32*32];
    __shared__ unsigned short Bs[2][128*32];
    __shared__ float CCs[32][132];
    __shared__ float qp[32][8];
    const int r0 = blockIdx.x * 32;
    const int tid = threadIdx.x, lane = tid & 63, wave = tid >> 6;
    const int wm = wave >> 1, wn = wave & 1;
    const int srow = tid >> 2, skc = (tid & 3) * 8;
    const int l15 = lane & 15, q8 = (lane >> 4) * 8;
    const unsigned short* gB0 = Bt + (size_t)srow * HID + skc;
    const unsigned short* gB1 = gB0 + 64 * HID;
    const unsigned short* gA = A + (size_t)(r0 + srow) * HID + skc;  // valid for tid<128
    f32x4 acc[4] = {};
    for (int k0 = 0; k0 < HID; k0 += 64) {
        if (tid < 128) {
            async16(gA + k0,      As[0] + tid*8);
            async16(gA + k0 + 32, As[1] + tid*8);
        }
        async16(gB0 + k0,      Bs[0] + tid*8);
        async16(gB1 + k0,      Bs[0] + 2048 + tid*8);
        async16(gB0 + k0 + 32, Bs[1] + tid*8);
        async16(gB1 + k0 + 32, Bs[1] + 2048 + tid*8);
        __syncthreads();
        #pragma unroll
        for (int h = 0; h < 2; ++h) {
            bf16x8 af = *(const bf16x8*)(As[h] + (wm*16 + l15) * 32 + q8);
            #pragma unroll
            for (int nt = 0; nt < 4; ++nt) {
                bf16x8 bfr = *(const bf16x8*)(Bs[h] + (wn*64 + nt*16 + l15) * 32 + q8);
                acc[nt] = __builtin_amdgcn_mfma_f32_16x16x32_bf16(af, bfr, acc[nt], 0, 0, 0);
            }
        }
        __syncthreads();
    }
    // epilogue: CC tile to LDS (add b3 + ctx residual)
    #pragma unroll
    for (int nt = 0; nt < 4; ++nt) {
        const int col = wn*64 + nt*16 + l15;
        const float bb = b3[col];
        #pragma unroll
        for (int r = 0; r < 4; ++r) {
            const int rowL = wm*16 + (lane >> 4)*4 + r;
            const int gb = (r0 + rowL) / NC;
            CCs[rowL][col] = acc[nt][r] + bb + ctx_cur[gb * CTXD + col];
        }
    }
    __syncthreads();
    // q reduction: 8 threads per row, 16 cols each
    {
        const int rowL = tid >> 3, seg = tid & 7;
        float s = 0.f;
        #pragma unroll
        for (int j = 0; j < 16; ++j) {
            const int col = seg*16 + j;
            s += CCs[rowL][col] * Wp[col];
        }
        qp[rowL][seg] = s;
    }
    __syncthreads();
    if (tid < 32) {
        const int gr = r0 + tid;
        const int gb = gr / NC, gc = gr - gb * NC;
        float s = qp[tid][0] + qp[tid][1] + qp[tid][2] + qp[tid][3]
                + qp[tid][4] + qp[tid][5] + qp[tid][6] + qp[tid][7];
        q[gb * QCOLS + (ii - 1) * NC + gc] = s + bp[0];
    }
    // ctx select: row with c == jidx[b][ii] becomes next context for batch b
    for (int rr = 0; rr < 32; ++rr) {
        const int gr = r0 + rr;
        const int gb = gr / NC, gc = gr - gb * NC;
        if (jidx[gb * ACT + ii] == gc) {
            if (tid < CTXD) ctx_nxt[gb * CTXD + tid] = CCs[rr][tid];
        }
    }
}

// ---------------- out[b] = logsumexp(q[b, 0:700]) ----------------------------
__global__ void lse_kernel(const float* __restrict__ q, float* __restrict__ out) {
    __shared__ float red[256];
    int b = blockIdx.x, t = threadIdx.x;
    float m = -INFINITY;
    for (int k = t; k < QCOLS; k += 256) m = fmaxf(m, q[b*QCOLS + k]);
    red[t] = m; __syncthreads();
    for (int s = 128; s > 0; s >>= 1) { if (t < s) red[t] = fmaxf(red[t], red[t+s]); __syncthreads(); }
    m = red[0]; __syncthreads();
    float sum = 0.0f;
    for (int k = t; k < QCOLS; k += 256) sum += expf(q[b*QCOLS + k] - m);
    red[t] = sum; __syncthreads();
    for (int s = 128; s > 0; s >>= 1) { if (t < s) red[t] += red[t+s]; __syncthreads(); }
    if (t == 0) out[b] = logf(red[0]) + m;
}

extern "C" void kernel_launch(void* const* d_in, const int* in_sizes, int n_in,
                              void* d_out, int out_size, void* d_ws, size_t ws_size,
                              hipStream_t stream) {
    const float* obs     = (const float*)d_in[0];
    const float* actions = (const float*)d_in[1];
    const float* W1      = (const float*)d_in[2];
    const float* b1      = (const float*)d_in[3];
    const float* W2      = (const float*)d_in[4];
    const float* b2      = (const float*)d_in[5];
    const float* W3      = (const float*)d_in[6];
    const float* b3      = (const float*)d_in[7];
    const float* Wp      = (const float*)d_in[8];
    const float* bp      = (const float*)d_in[9];
    float* out = (float*)d_out;
    float* ws  = (float*)d_ws;

    // workspace layout (float offsets)
    float* ctxA = ws;                                      // 16384
    float* ctxB = ws + 16384;                              // 16384
    float* q    = ws + 32768;                              // 89600
    int*   jidx = (int*)(ws + 122368);                     // 1024 slot
    unsigned short* obs_bf = (unsigned short*)(ws + 123392);   // 65536 us
    float* Yobs = ws + 156160;                             // 6*65536 = 393216
    unsigned short* W2T = (unsigned short*)(ws + 549376);  // 6*262144 us = 786432 f
    unsigned short* W3T = (unsigned short*)(ws + 1335808); // 6*65536 us = 196608 f
    unsigned short* H1  = (unsigned short*)(ws + 1532416); // 12800*512 us = 3276800 f
    unsigned short* H2  = (unsigned short*)(ws + 4809216); // 12800*512 us = 3276800 f
    unsigned short* W1AT = H2;  // alias: W1AT only read (yobs) before first gemm2 write of H2

    init_kernel<<<(BATCH*QCOLS + 255)/256, 256, 0, stream>>>(actions, ctxA, q, jidx);
    obscvt_kernel<<<BATCH*HID/256, 256, 0, stream>>>(obs, obs_bf);
    prep_transpose<<<dim3(16,16,18), dim3(32,8), 0, stream>>>(W1, W2, W3, W1AT, W2T, W3T);
    yobs_kernel<<<dim3(2,4,6), 256, 0, stream>>>(obs_bf, W1AT, b1, Yobs);

    float* cur = ctxA; float* nxt = ctxB;
    for (int i = 1; i < ACT; ++i) {
        const float* W1i = W1 + (size_t)i * 641 * HID;
        y0h1_kernel<<<BATCH*2, 256, 0, stream>>>(
            Yobs + (size_t)(i-1)*BATCH*HID, cur, W1i + (size_t)513*HID, W1i + (size_t)512*HID, H1);
        gemm2_kernel<<<dim3(NROWS/128, HID/128), 256, 0, stream>>>(
            H1, W2T + (size_t)(i-1)*262144, b2 + i*HID, H2);
        gemm3f_kernel<<<NROWS/32, 256, 0, stream>>>(
            H2, W3T + (size_t)(i-1)*65536, b3 + i*CTXD, cur, nxt, Wp, bp, jidx, q, i);
        float* tsw = cur; cur = nxt; nxt = tsw;
    }

    lse_kernel<<<BATCH, 256, 0, stream>>>(q, out);
}